// Round 13
// baseline (133.460 us; speedup 1.0000x reference)
//
#include <hip/hip_runtime.h>

#define NHEAD 4
#define NNODE 4096
#define DIM 256
#define NEGV (-9e15f)

typedef float        f32x4  __attribute__((ext_vector_type(4)));
typedef int          i32x4  __attribute__((ext_vector_type(4)));
typedef unsigned int u32x2  __attribute__((ext_vector_type(2)));
typedef unsigned int u32x4  __attribute__((ext_vector_type(4)));
typedef short        bf16x8 __attribute__((ext_vector_type(8)));
typedef float        f32x16 __attribute__((ext_vector_type(16)));

__device__ __forceinline__ unsigned int f2bf(float f) {
  unsigned int u = __float_as_uint(f);
  u += 0x7fffu + ((u >> 16) & 1u);   // RNE to bf16
  return u >> 16;
}

// ---- fused pre-pass: blocks 0..4095 adj->bitmask (vectorized), 4096..4351 xF ----
__global__ __launch_bounds__(256) void prep_all(const float* __restrict__ xg,
                                                const int* __restrict__ adj,
                                                unsigned short* __restrict__ xF,
                                                unsigned short* __restrict__ bits16) {
  const int blk = blockIdx.x;
  const int t = threadIdx.x;
  if (blk < 4096) {
    const int row = blk;
    const int* ap = adj + (size_t)row * NNODE + t * 16;
    const i32x4 j0 = *(const i32x4*)(ap);
    const i32x4 j1 = *(const i32x4*)(ap + 4);
    const i32x4 j2 = *(const i32x4*)(ap + 8);
    const i32x4 j3 = *(const i32x4*)(ap + 12);
    unsigned int m = 0;
#pragma unroll
    for (int k = 0; k < 4; ++k) {
      m |= (j0[k] > 0 ? 1u : 0u) << k;
      m |= (j1[k] > 0 ? 1u : 0u) << (4 + k);
      m |= (j2[k] > 0 ? 1u : 0u) << (8 + k);
      m |= (j3[k] > 0 ? 1u : 0u) << (12 + k);
    }
    bits16[(size_t)row * 256 + t] = (unsigned short)m;
  } else {
    __shared__ unsigned short tile[64 * 260];
    const int b = blk - 4096;
    const int h = b >> 6;
    const int it = b & 63;
    const int n = t >> 2;
    const int dsg = (t & 3) << 6;
    const float* src = xg + ((size_t)h * NNODE + (it << 6) + n) * DIM + dsg;
#pragma unroll
    for (int j = 0; j < 16; ++j) {
      const f32x4 v = *(const f32x4*)(src + 4 * j);
      u32x2 w;
      w[0] = f2bf(v[0]) | (f2bf(v[1]) << 16);
      w[1] = f2bf(v[2]) | (f2bf(v[3]) << 16);
      *(u32x2*)&tile[n * 260 + dsg + 4 * j] = w;
    }
    __syncthreads();
    const int d = t;
    unsigned short* ob = xF + ((size_t)((h << 6) + it) * 2048 + d) * 8;
#pragma unroll
    for (int ks = 0; ks < 4; ++ks)
#pragma unroll
      for (int lh = 0; lh < 2; ++lh) {
        bf16x8 val;
#pragma unroll
        for (int j = 0; j < 8; ++j) val[j] = (short)tile[(ks * 16 + lh * 8 + j) * 260 + d];
        *(bf16x8*)(ob + (size_t)(ks * 2 + lh) * 256 * 8) = val;
      }
  }
}

// ---- main v11: v8 with CT=128 (32 iterations, HALF the barriers).
// Tests the per-iteration fixed-overhead hypothesis: stream bytes, B bytes,
// MFMA count, LDS traffic all identical to v8 — only barrier count 64->32.
// 16 waves: kh=wv>>3 takes k-tile (2it+kh); d-slice (wv&7)*32.
__global__ __launch_bounds__(1024, 4) void gat_v11(
    const unsigned short* __restrict__ xF, const unsigned int* __restrict__ abits,
    const float* __restrict__ att, float* __restrict__ outg) {
  __shared__ unsigned short p_lds[2][16 * 64 * 8];  // 32 KB: [buf][slot][row^s][8]
  __shared__ float red_lds[8 * 8 * 64 * 4];         // 64 KB
  __shared__ float l_lds[64];

  const int t = threadIdx.x;
  const int lane = t & 63;
  const int flat = blockIdx.x;              // 0..255
  const int xcd = flat & 7;                 // round-robin XCD dispatch
  const int h   = xcd >> 1;                 // head pinned to an XCD pair
  const int rb  = ((xcd & 1) << 5) | (flat >> 3);   // 0..63
  const int r0  = rb * 64;

  // stream mapping: 16 threads/row, 8 cols each (128-col tile)
  const int sr = t >> 4;                    // 0..63
  const int c8 = (t & 15) << 3;             // 0..120
  const float* attb = att + ((size_t)h * NNODE + r0 + sr) * NNODE + c8;
  const unsigned int* ab = abits + (size_t)(r0 + sr) * 128 + (c8 >> 5);
  const int bsh = c8 & 31;                  // 0,8,16,24
  const int s_w = c8 >> 3;                  // P slot 0..15
  const int pwoff = s_w * 512 + ((sr ^ s_w) << 3);

  // mfma mapping: wave -> (k-tile parity kh, 32-wide d slice)
  const int wv   = t >> 6;                  // 0..15
  const int kh   = wv >> 3;                 // picks k-tile 2it+kh
  const int d0   = (wv & 7) << 5;
  const int lhi  = lane >> 5;
  const int lcol = lane & 31;
  int aoff0[4], aoff1[4];
#pragma unroll
  for (int ks = 0; ks < 4; ++ks) {
    const int s = kh * 8 + ks * 2 + lhi;    // slot 0..15
    aoff0[ks] = s * 512 + ((lcol ^ s) << 3);
    aoff1[ks] = s * 512 + (((32 + lcol) ^ s) << 3);
  }
  // B-frag base: k-tile (2it+kh), chunk (ks*2+lhi), d
  const unsigned short* xfb = xF + (size_t)h * 64 * 16384 + (size_t)kh * 16384
                                 + lhi * 2048 + (size_t)(d0 + lcol) * 8;

  f32x16 acc0 = {0.f};   // rows 0..31
  f32x16 acc1 = {0.f};   // rows 32..63
  float psum = 0.f;

  // prologue: B depth-1 (4 frags), att/bits depth-2
  bf16x8 xf0 = *(const bf16x8*)(xfb);
  bf16x8 xf1 = *(const bf16x8*)(xfb + 4096);
  bf16x8 xf2 = *(const bf16x8*)(xfb + 8192);
  bf16x8 xf3 = *(const bf16x8*)(xfb + 12288);
  f32x4 a0a = __builtin_nontemporal_load((const f32x4*)attb);
  f32x4 a0b = __builtin_nontemporal_load((const f32x4*)(attb + 4));
  f32x4 a1a = __builtin_nontemporal_load((const f32x4*)(attb + 128));
  f32x4 a1b = __builtin_nontemporal_load((const f32x4*)(attb + 132));
  unsigned int w0 = ab[0], w1 = ab[4];

  int buf = 0;
  for (int it = 0; it < 32; ++it) {
    // 1. B prefetch for it+1 (oldest this iter -> MFMA drain stops here)
    const int itn = (it + 1) & 31;
    const unsigned short* xfi = xfb + (size_t)itn * 32768;
    const bf16x8 nx0 = *(const bf16x8*)(xfi);
    const bf16x8 nx1 = *(const bf16x8*)(xfi + 4096);
    const bf16x8 nx2 = *(const bf16x8*)(xfi + 8192);
    const bf16x8 nx3 = *(const bf16x8*)(xfi + 12288);

    // 2. att/bits prefetch for it+2 (younger -> survives B drain)
    const int it2 = (it + 2) & 31;
    const f32x4 a2a = __builtin_nontemporal_load((const f32x4*)(attb + it2 * 128));
    const f32x4 a2b = __builtin_nontemporal_load((const f32x4*)(attb + it2 * 128 + 4));
    const unsigned int w2 = ab[it2 * 4];

    // 3. P = exp(lrelu masked) — shift-free softmax, 8 values/thread
    float e[8];
    {
      float sv[8];
      sv[0] = a0a[0]; sv[1] = a0a[1]; sv[2] = a0a[2]; sv[3] = a0a[3];
      sv[4] = a0b[0]; sv[5] = a0b[1]; sv[6] = a0b[2]; sv[7] = a0b[3];
#pragma unroll
      for (int k = 0; k < 8; ++k) {
        float s = sv[k];
        s = fmaxf(s, 0.2f * s);
        s = ((w0 >> (bsh + k)) & 1u) ? s : NEGV;
        e[k] = __expf(s);
        psum += e[k];
      }
    }
    u32x4 pk;
    pk[0] = f2bf(e[0]) | (f2bf(e[1]) << 16);
    pk[1] = f2bf(e[2]) | (f2bf(e[3]) << 16);
    pk[2] = f2bf(e[4]) | (f2bf(e[5]) << 16);
    pk[3] = f2bf(e[6]) | (f2bf(e[7]) << 16);
    *(u32x4*)&p_lds[buf][pwoff] = pk;   // one b128, slot-aligned

    // 4. own ds_write must land; global prefetches stay outstanding
    asm volatile("s_waitcnt lgkmcnt(0)" ::: "memory");
    __builtin_amdgcn_s_barrier();

    // 5. A-frags from LDS, 8 MFMAs with B(it) regs
    const unsigned short* pb = p_lds[buf];
    {
      const bf16x8 A00 = *(const bf16x8*)&pb[aoff0[0]];
      const bf16x8 A10 = *(const bf16x8*)&pb[aoff1[0]];
      const bf16x8 A01 = *(const bf16x8*)&pb[aoff0[1]];
      const bf16x8 A11 = *(const bf16x8*)&pb[aoff1[1]];
      __builtin_amdgcn_s_setprio(1);
      acc0 = __builtin_amdgcn_mfma_f32_32x32x16_bf16(A00, xf0, acc0, 0, 0, 0);
      acc1 = __builtin_amdgcn_mfma_f32_32x32x16_bf16(A10, xf0, acc1, 0, 0, 0);
      acc0 = __builtin_amdgcn_mfma_f32_32x32x16_bf16(A01, xf1, acc0, 0, 0, 0);
      acc1 = __builtin_amdgcn_mfma_f32_32x32x16_bf16(A11, xf1, acc1, 0, 0, 0);
      __builtin_amdgcn_s_setprio(0);
    }
    {
      const bf16x8 A02 = *(const bf16x8*)&pb[aoff0[2]];
      const bf16x8 A12 = *(const bf16x8*)&pb[aoff1[2]];
      const bf16x8 A03 = *(const bf16x8*)&pb[aoff0[3]];
      const bf16x8 A13 = *(const bf16x8*)&pb[aoff1[3]];
      __builtin_amdgcn_s_setprio(1);
      acc0 = __builtin_amdgcn_mfma_f32_32x32x16_bf16(A02, xf2, acc0, 0, 0, 0);
      acc1 = __builtin_amdgcn_mfma_f32_32x32x16_bf16(A12, xf2, acc1, 0, 0, 0);
      acc0 = __builtin_amdgcn_mfma_f32_32x32x16_bf16(A03, xf3, acc0, 0, 0, 0);
      acc1 = __builtin_amdgcn_mfma_f32_32x32x16_bf16(A13, xf3, acc1, 0, 0, 0);
      __builtin_amdgcn_s_setprio(0);
    }

    a0a = a1a; a0b = a1b; a1a = a2a; a1b = a2b;
    w0 = w1; w1 = w2;
    xf0 = nx0; xf1 = nx1; xf2 = nx2; xf3 = nx3;
    buf ^= 1;
  }

  // ---- epilogue (v8-identical) ----
  float l = psum;
  l += __shfl_xor(l, 1);
  l += __shfl_xor(l, 2);
  l += __shfl_xor(l, 4);
  l += __shfl_xor(l, 8);
  if ((t & 15) == 0) l_lds[sr] = l;
  if (kh == 1) {
    float* rbase = &red_lds[(size_t)(wv & 7) * 2048 + lane * 4];
#pragma unroll
    for (int j = 0; j < 4; ++j) {
      f32x4 v = {acc0[4 * j], acc0[4 * j + 1], acc0[4 * j + 2], acc0[4 * j + 3]};
      *(f32x4*)(rbase + (size_t)j * 256) = v;
    }
#pragma unroll
    for (int j = 0; j < 4; ++j) {
      f32x4 v = {acc1[4 * j], acc1[4 * j + 1], acc1[4 * j + 2], acc1[4 * j + 3]};
      *(f32x4*)(rbase + (size_t)(j + 4) * 256) = v;
    }
  }
  __syncthreads();
  if (kh == 0) {
    const float* rbase = &red_lds[(size_t)wv * 2048 + lane * 4];
#pragma unroll
    for (int j = 0; j < 4; ++j) {
      const f32x4 v = *(const f32x4*)(rbase + (size_t)j * 256);
      acc0[4 * j] += v[0]; acc0[4 * j + 1] += v[1];
      acc0[4 * j + 2] += v[2]; acc0[4 * j + 3] += v[3];
    }
#pragma unroll
    for (int j = 0; j < 4; ++j) {
      const f32x4 v = *(const f32x4*)(rbase + (size_t)(j + 4) * 256);
      acc1[4 * j] += v[0]; acc1[4 * j + 1] += v[1];
      acc1[4 * j + 2] += v[2]; acc1[4 * j + 3] += v[3];
    }
    float* outb = outg + ((size_t)h * NNODE + r0) * DIM + d0 + lcol;
#pragma unroll
    for (int q = 0; q < 4; ++q) {
      const int rbase0 = q * 8 + lhi * 4;
      const f32x4 lv0 = *(const f32x4*)&l_lds[rbase0];
      const f32x4 lv1 = *(const f32x4*)&l_lds[32 + rbase0];
#pragma unroll
      for (int i = 0; i < 4; ++i) {
        __builtin_nontemporal_store(acc0[q * 4 + i] / lv0[i],
                                    outb + (size_t)(rbase0 + i) * DIM);
        __builtin_nontemporal_store(acc1[q * 4 + i] / lv1[i],
                                    outb + (size_t)(32 + rbase0 + i) * DIM);
      }
    }
  }
}

// ---- small fallback: self-contained R1 kernel ----
__global__ __launch_bounds__(512, 4) void gat_fused(
    const float* __restrict__ xg, const int* __restrict__ adj,
    const float* __restrict__ att, float* __restrict__ outg) {
  __shared__ __align__(16) unsigned short p_l[64 * 64];
  __shared__ __align__(16) unsigned short xT_l[DIM * 64];
  __shared__ __align__(16) float fac_l[64];
  __shared__ __align__(16) float ll_l[64];
  const int t = threadIdx.x;
  const int lane = t & 63;
  const int flat = blockIdx.x;
  const int xcd  = flat & 7;
  const int h    = xcd >> 1;
  const int rb   = ((xcd & 1) << 5) | (flat >> 3);
  const int r0   = rb * 64;
  const int srow = t >> 3;
  const int sm0  = (t & 7) << 3;
  const float* attb = att + ((size_t)h * NNODE + (r0 + srow)) * NNODE + sm0;
  const int*   adjb = adj + (size_t)(r0 + srow) * NNODE + sm0;
  const int xm0 = (t >> 5) << 2;
  const int xd0 = (t & 31) << 2;
  const float* xb_h = xg + (size_t)h * NNODE * DIM;
  const int wv   = t >> 6;
  const int d0   = wv << 5;
  const int lhi  = lane >> 5;
  const int lcol = lane & 31;
  f32x16 acc0 = {0.f};
  f32x16 acc1 = {0.f};
  float m_run = -__builtin_inff();
  float l_run = 0.f;
  for (int it = 0; it < 64; ++it) {
    const int c0 = it * 64;
    {
      const f32x4 A0 = __builtin_nontemporal_load((const f32x4*)(attb + c0));
      const f32x4 A1 = __builtin_nontemporal_load((const f32x4*)(attb + c0) + 1);
      const i32x4 j0 = *((const i32x4*)(adjb + c0));
      const i32x4 j1 = *((const i32x4*)(adjb + c0) + 1);
      float sv[8];
      int   av[8];
#pragma unroll
      for (int k = 0; k < 4; ++k) { sv[k] = A0[k]; sv[4 + k] = A1[k]; av[k] = j0[k]; av[4 + k] = j1[k]; }
#pragma unroll
      for (int k = 0; k < 8; ++k) {
        float s = sv[k];
        s = s > 0.f ? s : 0.2f * s;
        sv[k] = (av[k] > 0) ? s : NEGV;
      }
      float tmax = sv[0];
#pragma unroll
      for (int k = 1; k < 8; ++k) tmax = fmaxf(tmax, sv[k]);
      tmax = fmaxf(tmax, __shfl_xor(tmax, 1));
      tmax = fmaxf(tmax, __shfl_xor(tmax, 2));
      tmax = fmaxf(tmax, __shfl_xor(tmax, 4));
      const float m_new = fmaxf(m_run, tmax);
      float ps = 0.f;
#pragma unroll
      for (int k = 0; k < 8; ++k) { sv[k] = __expf(sv[k] - m_new); ps += sv[k]; }
      ps += __shfl_xor(ps, 1);
      ps += __shfl_xor(ps, 2);
      ps += __shfl_xor(ps, 4);
      const float fac = __expf(m_run - m_new);
      l_run = l_run * fac + ps;
      m_run = m_new;
      if ((t & 7) == 0) fac_l[srow] = fac;
      u32x4 pk;
      pk[0] = f2bf(sv[0]) | (f2bf(sv[1]) << 16);
      pk[1] = f2bf(sv[2]) | (f2bf(sv[3]) << 16);
      pk[2] = f2bf(sv[4]) | (f2bf(sv[5]) << 16);
      pk[3] = f2bf(sv[6]) | (f2bf(sv[7]) << 16);
      *(u32x4*)&p_l[srow * 64 + (sm0 ^ ((srow & 7) << 3))] = pk;
    }
    {
      const float* xb = xb_h + (size_t)(c0 + xm0) * DIM;
#pragma unroll
      for (int hh2 = 0; hh2 < 2; ++hh2) {
        const int dbase = xd0 + hh2 * 128;
        const f32x4 r0v = *(const f32x4*)(xb + dbase);
        const f32x4 r1v = *(const f32x4*)(xb + DIM + dbase);
        const f32x4 r2v = *(const f32x4*)(xb + 2 * DIM + dbase);
        const f32x4 r3v = *(const f32x4*)(xb + 3 * DIM + dbase);
#pragma unroll
        for (int j = 0; j < 4; ++j) {
          const int d = dbase + j;
          u32x2 wds;
          wds[0] = f2bf(r0v[j]) | (f2bf(r1v[j]) << 16);
          wds[1] = f2bf(r2v[j]) | (f2bf(r3v[j]) << 16);
          *(u32x2*)&xT_l[d * 64 + (xm0 ^ (((d >> 2) & 7) << 3))] = wds;
        }
      }
    }
    __syncthreads();
    {
#pragma unroll
      for (int q = 0; q < 4; ++q) {
        const f32x4 fa = *(const f32x4*)&fac_l[q * 8 + lhi * 4];
        const f32x4 fb = *(const f32x4*)&fac_l[32 + q * 8 + lhi * 4];
#pragma unroll
        for (int i = 0; i < 4; ++i) { acc0[q * 4 + i] *= fa[i]; acc1[q * 4 + i] *= fb[i]; }
      }
#pragma unroll
      for (int ks = 0; ks < 4; ++ks) {
        const int mk = ks * 16 + lhi * 8;
        const bf16x8 afA = *(const bf16x8*)&p_l[lcol * 64 + (mk ^ ((lcol & 7) << 3))];
        const bf16x8 afB = *(const bf16x8*)&p_l[(32 + lcol) * 64 + (mk ^ ((lcol & 7) << 3))];
        const int dd = d0 + lcol;
        const bf16x8 bfr = *(const bf16x8*)&xT_l[dd * 64 + (mk ^ (((dd >> 2) & 7) << 3))];
        acc0 = __builtin_amdgcn_mfma_f32_32x32x16_bf16(afA, bfr, acc0, 0, 0, 0);
        acc1 = __builtin_amdgcn_mfma_f32_32x32x16_bf16(afB, bfr, acc1, 0, 0, 0);
      }
    }
    __syncthreads();
  }
  if ((t & 7) == 0) ll_l[srow] = l_run;
  __syncthreads();
  float* outb = outg + (size_t)h * NNODE * DIM + (size_t)r0 * DIM + d0 + lcol;
#pragma unroll
  for (int q = 0; q < 4; ++q) {
    const f32x4 la = *(const f32x4*)&ll_l[q * 8 + lhi * 4];
    const f32x4 lb = *(const f32x4*)&ll_l[32 + q * 8 + lhi * 4];
    const int rbase = q * 8 + lhi * 4;
#pragma unroll
    for (int i = 0; i < 4; ++i) {
      __builtin_nontemporal_store(acc0[q * 4 + i] / la[i], outb + (size_t)(rbase + i) * DIM);
      __builtin_nontemporal_store(acc1[q * 4 + i] / lb[i], outb + (size_t)(32 + rbase + i) * DIM);
    }
  }
}

extern "C" void kernel_launch(void* const* d_in, const int* in_sizes, int n_in,
                              void* d_out, int out_size, void* d_ws, size_t ws_size,
                              hipStream_t stream) {
  const float* xg  = (const float*)d_in[0];
  const int*   adj = (const int*)d_in[1];
  const float* att = (const float*)d_in[2];
  float*       outg = (float*)d_out;
  const size_t xf_bytes = (size_t)NHEAD * DIM * NNODE * 2;   // 8 MB
  const size_t ab_bytes = (size_t)NNODE * 128 * 4;           // 2 MB
  if (ws_size >= xf_bytes + ab_bytes) {
    unsigned short* xF    = (unsigned short*)d_ws;
    unsigned int*   abits = (unsigned int*)((char*)d_ws + xf_bytes);
    prep_all<<<dim3(4096 + 256), dim3(256), 0, stream>>>(xg, adj, xF,
                                                         (unsigned short*)abits);
    gat_v11<<<dim3(256), dim3(1024), 0, stream>>>(xF, abits, att, outg);
  } else {
    gat_fused<<<dim3(256), dim3(512), 0, stream>>>(xg, adj, att, outg);
  }
}

// Round 14
// 106.464 us; speedup vs baseline: 1.2536x; 1.2536x over previous
//
#include <hip/hip_runtime.h>

#define NHEAD 4
#define NNODE 4096
#define DIM 256
#define ROWS 64
#define CT 64
#define NT (NNODE / CT)
#define NEGV (-9e15f)

typedef float        f32x4  __attribute__((ext_vector_type(4)));
typedef int          i32x4  __attribute__((ext_vector_type(4)));
typedef unsigned int u32x2  __attribute__((ext_vector_type(2)));
typedef unsigned int u32x4  __attribute__((ext_vector_type(4)));
typedef short        bf16x8 __attribute__((ext_vector_type(8)));
typedef float        f32x16 __attribute__((ext_vector_type(16)));

__device__ __forceinline__ unsigned int f2bf(float f) {
  unsigned int u = __float_as_uint(f);
  u += 0x7fffu + ((u >> 16) & 1u);   // RNE to bf16
  return u >> 16;
}

// ---- fused pre-pass: blocks 0..4095 adj->bitmask (vectorized), 4096..4351 xF ----
__global__ __launch_bounds__(256) void prep_all(const float* __restrict__ xg,
                                                const int* __restrict__ adj,
                                                unsigned short* __restrict__ xF,
                                                unsigned short* __restrict__ bits16) {
  const int blk = blockIdx.x;
  const int t = threadIdx.x;
  if (blk < 4096) {
    const int row = blk;
    const int* ap = adj + (size_t)row * NNODE + t * 16;
    const i32x4 j0 = *(const i32x4*)(ap);
    const i32x4 j1 = *(const i32x4*)(ap + 4);
    const i32x4 j2 = *(const i32x4*)(ap + 8);
    const i32x4 j3 = *(const i32x4*)(ap + 12);
    unsigned int m = 0;
#pragma unroll
    for (int k = 0; k < 4; ++k) {
      m |= (j0[k] > 0 ? 1u : 0u) << k;
      m |= (j1[k] > 0 ? 1u : 0u) << (4 + k);
      m |= (j2[k] > 0 ? 1u : 0u) << (8 + k);
      m |= (j3[k] > 0 ? 1u : 0u) << (12 + k);
    }
    bits16[(size_t)row * 256 + t] = (unsigned short)m;
  } else {
    __shared__ unsigned short tile[64 * 260];
    const int b = blk - 4096;
    const int h = b >> 6;
    const int it = b & 63;
    const int n = t >> 2;
    const int dsg = (t & 3) << 6;
    const float* src = xg + ((size_t)h * NNODE + (it << 6) + n) * DIM + dsg;
#pragma unroll
    for (int j = 0; j < 16; ++j) {
      const f32x4 v = *(const f32x4*)(src + 4 * j);
      u32x2 w;
      w[0] = f2bf(v[0]) | (f2bf(v[1]) << 16);
      w[1] = f2bf(v[2]) | (f2bf(v[3]) << 16);
      *(u32x2*)&tile[n * 260 + dsg + 4 * j] = w;
    }
    __syncthreads();
    const int d = t;
    unsigned short* ob = xF + ((size_t)((h << 6) + it) * 2048 + d) * 8;
#pragma unroll
    for (int ks = 0; ks < 4; ++ks)
#pragma unroll
      for (int lh = 0; lh < 2; ++lh) {
        bf16x8 val;
#pragma unroll
        for (int j = 0; j < 8; ++j) val[j] = (short)tile[(ks * 16 + lh * 8 + j) * 260 + d];
        *(bf16x8*)(ob + (size_t)(ks * 2 + lh) * 256 * 8) = val;
      }
  }
}

// ---- main v8 (best measured: 106.6 us total). 64 rows/block, 1024 thr,
// grid 256 (1/CU). 16 waves: kh k-half split, reduced once in epilogue;
// transposed conflict-free P layout; B(it+1) issued before att(it+2) so the
// MFMA drain of B(it) leaves att outstanding. Shift-free softmax.
__global__ __launch_bounds__(1024, 4) void gat_v8(
    const unsigned short* __restrict__ xF, const unsigned int* __restrict__ abits,
    const float* __restrict__ att, float* __restrict__ outg) {
  __shared__ unsigned short p_lds[2][8 * 64 * 8];  // 16 KB: [buf][s][r^s][8]
  __shared__ float red_lds[8 * 8 * 64 * 4];        // 64 KB
  __shared__ float l_lds[ROWS];

  const int t = threadIdx.x;
  const int lane = t & 63;
  const int flat = blockIdx.x;              // 0..255
  const int xcd = flat & 7;                 // round-robin XCD dispatch
  const int h   = xcd >> 1;                 // head pinned to an XCD pair
  const int rb  = ((xcd & 1) << 5) | (flat >> 3);   // 0..63
  const int r0  = rb * ROWS;

  // score mapping: 16 threads/row, 4 cols each
  const int sr  = t >> 4;                   // 0..63
  const int c4  = (t & 15) << 2;            // 0..60
  const float* attb = att + ((size_t)h * NNODE + r0 + sr) * NNODE + c4;
  const unsigned int* ab = abits + (size_t)(r0 + sr) * 128 + (c4 >> 5);
  const int bsh = c4 & 31;
  // transposed-P write offset: slot s=c4>>3, row sr XOR s, sub-off c4&7 shorts
  const int ws_  = c4 >> 3;
  const int pwoff = ws_ * 512 + ((sr ^ ws_) << 3) + (c4 & 7);

  // mfma mapping: wave -> (k-half, 32-wide d slice)
  const int wv   = t >> 6;                  // 0..15
  const int kh   = wv >> 3;                 // 0..1  k-half
  const int d0   = (wv & 7) << 5;           // 0..224
  const int lhi  = lane >> 5;
  const int lcol = lane & 31;
  // A-frag slots: s = kh*4 + ks*2 + lhi; addr = s*512 + ((rt*32+lcol)^s)*8
  const int s0 = kh * 4 + lhi;              // ks=0
  const int s1 = kh * 4 + 2 + lhi;          // ks=1
  const int aoff00 = s0 * 512 + ((lcol ^ s0) << 3);
  const int aoff01 = s1 * 512 + ((lcol ^ s1) << 3);
  const int aoff10 = s0 * 512 + (((32 + lcol) ^ s0) << 3);
  const int aoff11 = s1 * 512 + (((32 + lcol) ^ s1) << 3);
  // B-frag base
  const unsigned short* xfb = xF + (size_t)h * NT * 16384 + kh * 8192
                                 + lhi * 2048 + (size_t)(d0 + lcol) * 8;

  f32x16 acc0 = {0.f};   // rows 0..31 of band
  f32x16 acc1 = {0.f};   // rows 32..63
  float psum = 0.f;

  // prologue: B depth-1, att/bits depth-2
  bf16x8 xf0 = *(const bf16x8*)(xfb);
  bf16x8 xf1 = *(const bf16x8*)(xfb + 4096);
  f32x4 a0 = __builtin_nontemporal_load((const f32x4*)attb);
  f32x4 a1 = __builtin_nontemporal_load((const f32x4*)(attb + CT));
  unsigned int w0 = ab[0], w1 = ab[2];

  int buf = 0;
  for (int it = 0; it < NT; ++it) {
    // 1. B prefetch for it+1 (OLDEST this iter -> MFMA drain stops here)
    const int itn = (it + 1) & (NT - 1);
    const unsigned short* xfi = xfb + (size_t)itn * 16384;
    const bf16x8 nx0 = *(const bf16x8*)(xfi);
    const bf16x8 nx1 = *(const bf16x8*)(xfi + 4096);

    // 2. att/bits prefetch for it+2 (younger -> survives the B drain)
    const int it2 = (it + 2) & (NT - 1);
    const f32x4 a2 = __builtin_nontemporal_load((const f32x4*)(attb + it2 * CT));
    const unsigned int w2 = ab[it2 << 1];

    // 3. P = exp(lrelu masked) — shift-free softmax
    float e0, e1, e2, e3;
    {
      float s0v = a0[0], s1v = a0[1], s2v = a0[2], s3v = a0[3];
      s0v = fmaxf(s0v, 0.2f * s0v); s1v = fmaxf(s1v, 0.2f * s1v);
      s2v = fmaxf(s2v, 0.2f * s2v); s3v = fmaxf(s3v, 0.2f * s3v);
      s0v = ((w0 >> (bsh + 0)) & 1u) ? s0v : NEGV;
      s1v = ((w0 >> (bsh + 1)) & 1u) ? s1v : NEGV;
      s2v = ((w0 >> (bsh + 2)) & 1u) ? s2v : NEGV;
      s3v = ((w0 >> (bsh + 3)) & 1u) ? s3v : NEGV;
      e0 = __expf(s0v); e1 = __expf(s1v); e2 = __expf(s2v); e3 = __expf(s3v);
      psum += (e0 + e1) + (e2 + e3);
    }
    u32x2 pk;
    pk[0] = f2bf(e0) | (f2bf(e1) << 16);
    pk[1] = f2bf(e2) | (f2bf(e3) << 16);
    *(u32x2*)&p_lds[buf][pwoff] = pk;

    // 4. own ds_write must land; global prefetches stay outstanding
    asm volatile("s_waitcnt lgkmcnt(0)" ::: "memory");
    __builtin_amdgcn_s_barrier();

    // 5. A-frags from LDS, MFMA with B(it) regs
    const unsigned short* pb = p_lds[buf];
    const bf16x8 A00 = *(const bf16x8*)&pb[aoff00];
    const bf16x8 A01 = *(const bf16x8*)&pb[aoff01];
    const bf16x8 A10 = *(const bf16x8*)&pb[aoff10];
    const bf16x8 A11 = *(const bf16x8*)&pb[aoff11];
    __builtin_amdgcn_s_setprio(1);
    acc0 = __builtin_amdgcn_mfma_f32_32x32x16_bf16(A00, xf0, acc0, 0, 0, 0);
    acc0 = __builtin_amdgcn_mfma_f32_32x32x16_bf16(A01, xf1, acc0, 0, 0, 0);
    acc1 = __builtin_amdgcn_mfma_f32_32x32x16_bf16(A10, xf0, acc1, 0, 0, 0);
    acc1 = __builtin_amdgcn_mfma_f32_32x32x16_bf16(A11, xf1, acc1, 0, 0, 0);
    __builtin_amdgcn_s_setprio(0);

    a0 = a1; a1 = a2; w0 = w1; w1 = w2;
    xf0 = nx0; xf1 = nx1;
    buf ^= 1;
  }

  // ---- epilogue ----
  float l = psum;
  l += __shfl_xor(l, 1);
  l += __shfl_xor(l, 2);
  l += __shfl_xor(l, 4);
  l += __shfl_xor(l, 8);
  if ((t & 15) == 0) l_lds[sr] = l;
  if (kh == 1) {
    float* rbase = &red_lds[(size_t)(wv & 7) * 2048 + lane * 4];
#pragma unroll
    for (int j = 0; j < 4; ++j) {
      f32x4 v = {acc0[4 * j], acc0[4 * j + 1], acc0[4 * j + 2], acc0[4 * j + 3]};
      *(f32x4*)(rbase + (size_t)j * 256) = v;
    }
#pragma unroll
    for (int j = 0; j < 4; ++j) {
      f32x4 v = {acc1[4 * j], acc1[4 * j + 1], acc1[4 * j + 2], acc1[4 * j + 3]};
      *(f32x4*)(rbase + (size_t)(j + 4) * 256) = v;
    }
  }
  __syncthreads();
  if (kh == 0) {
    const float* rbase = &red_lds[(size_t)wv * 2048 + lane * 4];
#pragma unroll
    for (int j = 0; j < 4; ++j) {
      const f32x4 v = *(const f32x4*)(rbase + (size_t)j * 256);
      acc0[4 * j] += v[0]; acc0[4 * j + 1] += v[1];
      acc0[4 * j + 2] += v[2]; acc0[4 * j + 3] += v[3];
    }
#pragma unroll
    for (int j = 0; j < 4; ++j) {
      const f32x4 v = *(const f32x4*)(rbase + (size_t)(j + 4) * 256);
      acc1[4 * j] += v[0]; acc1[4 * j + 1] += v[1];
      acc1[4 * j + 2] += v[2]; acc1[4 * j + 3] += v[3];
    }
    float* outb = outg + ((size_t)h * NNODE + r0) * DIM + d0 + lcol;
#pragma unroll
    for (int q = 0; q < 4; ++q) {
      const int rbase0 = q * 8 + lhi * 4;
      const f32x4 lv0 = *(const f32x4*)&l_lds[rbase0];
      const f32x4 lv1 = *(const f32x4*)&l_lds[32 + rbase0];
#pragma unroll
      for (int i = 0; i < 4; ++i) {
        __builtin_nontemporal_store(acc0[q * 4 + i] / lv0[i],
                                    outb + (size_t)(rbase0 + i) * DIM);
        __builtin_nontemporal_store(acc1[q * 4 + i] / lv1[i],
                                    outb + (size_t)(32 + rbase0 + i) * DIM);
      }
    }
  }
}

// ---- small fallback: self-contained R1 kernel ----
__global__ __launch_bounds__(512, 4) void gat_fused(
    const float* __restrict__ xg, const int* __restrict__ adj,
    const float* __restrict__ att, float* __restrict__ outg) {
  __shared__ __align__(16) unsigned short p_l[64 * 64];
  __shared__ __align__(16) unsigned short xT_l[DIM * 64];
  __shared__ __align__(16) float fac_l[64];
  __shared__ __align__(16) float ll_l[64];
  const int t = threadIdx.x;
  const int lane = t & 63;
  const int flat = blockIdx.x;
  const int xcd  = flat & 7;
  const int h    = xcd >> 1;
  const int rb   = ((xcd & 1) << 5) | (flat >> 3);
  const int r0   = rb * 64;
  const int srow = t >> 3;
  const int sm0  = (t & 7) << 3;
  const float* attb = att + ((size_t)h * NNODE + (r0 + srow)) * NNODE + sm0;
  const int*   adjb = adj + (size_t)(r0 + srow) * NNODE + sm0;
  const int xm0 = (t >> 5) << 2;
  const int xd0 = (t & 31) << 2;
  const float* xb_h = xg + (size_t)h * NNODE * DIM;
  const int wv   = t >> 6;
  const int d0   = wv << 5;
  const int lhi  = lane >> 5;
  const int lcol = lane & 31;
  f32x16 acc0 = {0.f};
  f32x16 acc1 = {0.f};
  float m_run = -__builtin_inff();
  float l_run = 0.f;
  for (int it = 0; it < 64; ++it) {
    const int c0 = it * 64;
    {
      const f32x4 A0 = __builtin_nontemporal_load((const f32x4*)(attb + c0));
      const f32x4 A1 = __builtin_nontemporal_load((const f32x4*)(attb + c0) + 1);
      const i32x4 j0 = *((const i32x4*)(adjb + c0));
      const i32x4 j1 = *((const i32x4*)(adjb + c0) + 1);
      float sv[8];
      int   av[8];
#pragma unroll
      for (int k = 0; k < 4; ++k) { sv[k] = A0[k]; sv[4 + k] = A1[k]; av[k] = j0[k]; av[4 + k] = j1[k]; }
#pragma unroll
      for (int k = 0; k < 8; ++k) {
        float s = sv[k];
        s = s > 0.f ? s : 0.2f * s;
        sv[k] = (av[k] > 0) ? s : NEGV;
      }
      float tmax = sv[0];
#pragma unroll
      for (int k = 1; k < 8; ++k) tmax = fmaxf(tmax, sv[k]);
      tmax = fmaxf(tmax, __shfl_xor(tmax, 1));
      tmax = fmaxf(tmax, __shfl_xor(tmax, 2));
      tmax = fmaxf(tmax, __shfl_xor(tmax, 4));
      const float m_new = fmaxf(m_run, tmax);
      float ps = 0.f;
#pragma unroll
      for (int k = 0; k < 8; ++k) { sv[k] = __expf(sv[k] - m_new); ps += sv[k]; }
      ps += __shfl_xor(ps, 1);
      ps += __shfl_xor(ps, 2);
      ps += __shfl_xor(ps, 4);
      const float fac = __expf(m_run - m_new);
      l_run = l_run * fac + ps;
      m_run = m_new;
      if ((t & 7) == 0) fac_l[srow] = fac;
      u32x4 pk;
      pk[0] = f2bf(sv[0]) | (f2bf(sv[1]) << 16);
      pk[1] = f2bf(sv[2]) | (f2bf(sv[3]) << 16);
      pk[2] = f2bf(sv[4]) | (f2bf(sv[5]) << 16);
      pk[3] = f2bf(sv[6]) | (f2bf(sv[7]) << 16);
      *(u32x4*)&p_l[srow * 64 + (sm0 ^ ((srow & 7) << 3))] = pk;
    }
    {
      const float* xb = xb_h + (size_t)(c0 + xm0) * DIM;
#pragma unroll
      for (int hh2 = 0; hh2 < 2; ++hh2) {
        const int dbase = xd0 + hh2 * 128;
        const f32x4 r0v = *(const f32x4*)(xb + dbase);
        const f32x4 r1v = *(const f32x4*)(xb + DIM + dbase);
        const f32x4 r2v = *(const f32x4*)(xb + 2 * DIM + dbase);
        const f32x4 r3v = *(const f32x4*)(xb + 3 * DIM + dbase);
#pragma unroll
        for (int j = 0; j < 4; ++j) {
          const int d = dbase + j;
          u32x2 wds;
          wds[0] = f2bf(r0v[j]) | (f2bf(r1v[j]) << 16);
          wds[1] = f2bf(r2v[j]) | (f2bf(r3v[j]) << 16);
          *(u32x2*)&xT_l[d * 64 + (xm0 ^ (((d >> 2) & 7) << 3))] = wds;
        }
      }
    }
    __syncthreads();
    {
#pragma unroll
      for (int q = 0; q < 4; ++q) {
        const f32x4 fa = *(const f32x4*)&fac_l[q * 8 + lhi * 4];
        const f32x4 fb = *(const f32x4*)&fac_l[32 + q * 8 + lhi * 4];
#pragma unroll
        for (int i = 0; i < 4; ++i) { acc0[q * 4 + i] *= fa[i]; acc1[q * 4 + i] *= fb[i]; }
      }
#pragma unroll
      for (int ks = 0; ks < 4; ++ks) {
        const int mk = ks * 16 + lhi * 8;
        const bf16x8 afA = *(const bf16x8*)&p_l[lcol * 64 + (mk ^ ((lcol & 7) << 3))];
        const bf16x8 afB = *(const bf16x8*)&p_l[(32 + lcol) * 64 + (mk ^ ((lcol & 7) << 3))];
        const int dd = d0 + lcol;
        const bf16x8 bfr = *(const bf16x8*)&xT_l[dd * 64 + (mk ^ (((dd >> 2) & 7) << 3))];
        acc0 = __builtin_amdgcn_mfma_f32_32x32x16_bf16(afA, bfr, acc0, 0, 0, 0);
        acc1 = __builtin_amdgcn_mfma_f32_32x32x16_bf16(afB, bfr, acc1, 0, 0, 0);
      }
    }
    __syncthreads();
  }
  if ((t & 7) == 0) ll_l[srow] = l_run;
  __syncthreads();
  float* outb = outg + (size_t)h * NNODE * DIM + (size_t)r0 * DIM + d0 + lcol;
#pragma unroll
  for (int q = 0; q < 4; ++q) {
    const f32x4 la = *(const f32x4*)&ll_l[q * 8 + lhi * 4];
    const f32x4 lb = *(const f32x4*)&ll_l[32 + q * 8 + lhi * 4];
    const int rbase = q * 8 + lhi * 4;
#pragma unroll
    for (int i = 0; i < 4; ++i) {
      __builtin_nontemporal_store(acc0[q * 4 + i] / la[i], outb + (size_t)(rbase + i) * DIM);
      __builtin_nontemporal_store(acc1[q * 4 + i] / lb[i], outb + (size_t)(32 + rbase + i) * DIM);
    }
  }
}

extern "C" void kernel_launch(void* const* d_in, const int* in_sizes, int n_in,
                              void* d_out, int out_size, void* d_ws, size_t ws_size,
                              hipStream_t stream) {
  const float* xg  = (const float*)d_in[0];
  const int*   adj = (const int*)d_in[1];
  const float* att = (const float*)d_in[2];
  float*       outg = (float*)d_out;
  const size_t xf_bytes = (size_t)NHEAD * DIM * NNODE * 2;   // 8 MB
  const size_t ab_bytes = (size_t)NNODE * 128 * 4;           // 2 MB
  if (ws_size >= xf_bytes + ab_bytes) {
    unsigned short* xF    = (unsigned short*)d_ws;
    unsigned int*   abits = (unsigned int*)((char*)d_ws + xf_bytes);
    prep_all<<<dim3(4096 + 256), dim3(256), 0, stream>>>(xg, adj, xF,
                                                         (unsigned short*)abits);
    gat_v8<<<dim3(256), dim3(1024), 0, stream>>>(xF, abits, att, outg);
  } else {
    gat_fused<<<dim3(256), dim3(512), 0, stream>>>(xg, adj, att, outg);
  }
}